// Round 1
// baseline (1243.026 us; speedup 1.0000x reference)
//
#include <hip/hip_runtime.h>

constexpr int NP = 12288;   // N points
constexpr int NB = 4;       // batches
constexpr int MC = 1024;    // M context
constexpr int DM = 256;     // D
constexpr int KVD = 512;    // KV feature dim
constexpr int NH = 8;       // heads
constexpr int DH = 32;      // head dim
constexpr int RT = 8;       // rows per attention block

// starts[b] = lower_bound(batch_idx, b); starts[NB] = NP
__global__ void k_starts(const int* __restrict__ bidx, int* __restrict__ starts) {
    int b = threadIdx.x;
    if (b > NB) return;
    int lo = 0, hi = NP;
    while (lo < hi) { int mid = (lo + hi) >> 1; if (bidx[mid] < b) lo = mid + 1; else hi = mid; }
    starts[b] = lo;
}

// y = LN(x [+ x2]) * g + b   ; one row (DM=256) per block, 256 threads
__global__ __launch_bounds__(256) void k_ln(const float* __restrict__ x,
        const float* __restrict__ x2, const float* __restrict__ g,
        const float* __restrict__ bb, float* __restrict__ y) {
    int row = blockIdx.x, t = threadIdx.x;
    float v = x[row * DM + t];
    if (x2) v += x2[row * DM + t];
    __shared__ float red[4];
    float s = v;
#pragma unroll
    for (int o = 1; o < 64; o <<= 1) s += __shfl_xor(s, o);
    if ((t & 63) == 0) red[t >> 6] = s;
    __syncthreads();
    float mu = (red[0] + red[1] + red[2] + red[3]) * (1.0f / DM);
    __syncthreads();
    float dv = v - mu;
    s = dv * dv;
#pragma unroll
    for (int o = 1; o < 64; o <<= 1) s += __shfl_xor(s, o);
    if ((t & 63) == 0) red[t >> 6] = s;
    __syncthreads();
    float var = (red[0] + red[1] + red[2] + red[3]) * (1.0f / DM);
    y[row * DM + t] = dv * rsqrtf(var + 1e-5f) * g[t] + bb[t];
}

// C[r,c] = sum_k A[r,k] * W[c,k] + bias[c]
// A: [Mr, K] row-major, W: [Nc, K] row-major. Mr%64==0, Nc%64==0, K%16==0.
__global__ __launch_bounds__(256) void k_gemm_bt(const float* __restrict__ A,
        const float* __restrict__ W, const float* __restrict__ bias,
        float* __restrict__ C, int K, int Nc) {
    __shared__ float As[64][17];
    __shared__ float Bs[64][17];
    int t = threadIdx.x;
    int tx = t & 15, ty = t >> 4;
    int row0 = blockIdx.y * 64, col0 = blockIdx.x * 64;
    float acc[4][4] = {};
    int lr = t >> 4, lc = t & 15;
    for (int k0 = 0; k0 < K; k0 += 16) {
#pragma unroll
        for (int j = 0; j < 4; ++j) {
            As[lr + j * 16][lc] = A[(size_t)(row0 + lr + j * 16) * K + k0 + lc];
            Bs[lr + j * 16][lc] = W[(size_t)(col0 + lr + j * 16) * K + k0 + lc];
        }
        __syncthreads();
#pragma unroll
        for (int kk = 0; kk < 16; ++kk) {
            float a[4], b[4];
#pragma unroll
            for (int i = 0; i < 4; ++i) a[i] = As[ty * 4 + i][kk];
#pragma unroll
            for (int j = 0; j < 4; ++j) b[j] = Bs[tx * 4 + j][kk];
#pragma unroll
            for (int i = 0; i < 4; ++i)
#pragma unroll
                for (int j = 0; j < 4; ++j) acc[i][j] += a[i] * b[j];
        }
        __syncthreads();
    }
#pragma unroll
    for (int i = 0; i < 4; ++i)
#pragma unroll
        for (int j = 0; j < 4; ++j) {
            int c = col0 + tx * 4 + j;
            C[(size_t)(row0 + ty * 4 + i) * Nc + c] = acc[i][j] + bias[c];
        }
}

// Cross-attention: 8 rows per block, 256 threads.
// LDS: qs[8][256], S[8][1024], KVt[32][33] (padded -> conflict-free)
__global__ __launch_bounds__(256) void k_attn(const float* __restrict__ q,
        const float* __restrict__ Kc, const float* __restrict__ Vc,
        const int* __restrict__ starts, float* __restrict__ o) {
    int b = blockIdx.y;
    int r0 = starts[b] + blockIdx.x * RT;
    int rend = starts[b + 1];
    if (r0 >= rend) return;
    int nr = min(RT, rend - r0);

    __shared__ float qs[RT][DM];
    __shared__ float S[RT][MC];
    __shared__ float KVt[32][33];

    int t = threadIdx.x;
    for (int i = t; i < RT * DM; i += 256) {
        int r = i >> 8, d = i & 255;
        qs[r][d] = (r < nr) ? q[(size_t)(r0 + r) * DM + d] : 0.f;
    }
    const float* Kb = Kc + (size_t)b * MC * DM;
    const float* Vb = Vc + (size_t)b * MC * DM;
    const float scale = 0.17677669529663687f;  // 1/sqrt(32)
    int rr = t >> 5, cc = t & 31;
    int smi = t >> 3, sdi = (t & 7) << 2;      // staging: row, col4

    for (int h = 0; h < NH; ++h) {
        // ---- scores: S[r][m] = (q_r . K_m)_head_h * scale ----
        for (int mt = 0; mt < MC / 32; ++mt) {
            float4 kv = *(const float4*)&Kb[(size_t)(mt * 32 + smi) * DM + h * DH + sdi];
            __syncthreads();  // prior readers of KVt / qs-producers done
            KVt[smi][sdi + 0] = kv.x; KVt[smi][sdi + 1] = kv.y;
            KVt[smi][sdi + 2] = kv.z; KVt[smi][sdi + 3] = kv.w;
            __syncthreads();
            float acc = 0.f;
#pragma unroll
            for (int d = 0; d < DH; d += 4) {
                float4 qa = *(const float4*)&qs[rr][h * DH + d];  // broadcast per 32-group
                acc += qa.x * KVt[cc][d] + qa.y * KVt[cc][d + 1]
                     + qa.z * KVt[cc][d + 2] + qa.w * KVt[cc][d + 3];
            }
            S[rr][mt * 32 + cc] = acc * scale;
        }
        __syncthreads();
        // ---- softmax over m (each (rr,cc) owns columns cc+32j of its row) ----
        float mx = -1e30f;
        for (int m = cc; m < MC; m += 32) mx = fmaxf(mx, S[rr][m]);
#pragma unroll
        for (int o2 = 1; o2 < 32; o2 <<= 1) mx = fmaxf(mx, __shfl_xor(mx, o2));
        float sum = 0.f;
        for (int m = cc; m < MC; m += 32) {
            float e = __expf(S[rr][m] - mx);
            S[rr][m] = e; sum += e;
        }
#pragma unroll
        for (int o2 = 1; o2 < 32; o2 <<= 1) sum += __shfl_xor(sum, o2);
        float inv = 1.0f / sum;
        for (int m = cc; m < MC; m += 32) S[rr][m] *= inv;
        __syncthreads();
        // ---- PV: o[r][h*32+cc] = sum_m p[r][m] * V[m][h*32+cc] ----
        float oacc = 0.f;
        for (int mt = 0; mt < MC / 32; ++mt) {
            float4 vv = *(const float4*)&Vb[(size_t)(mt * 32 + smi) * DM + h * DH + sdi];
            __syncthreads();
            KVt[smi][sdi + 0] = vv.x; KVt[smi][sdi + 1] = vv.y;
            KVt[smi][sdi + 2] = vv.z; KVt[smi][sdi + 3] = vv.w;
            __syncthreads();
#pragma unroll
            for (int mi = 0; mi < 32; ++mi)
                oacc += S[rr][mt * 32 + mi] * KVt[mi][cc];
        }
        __syncthreads();
        if (rr < nr) o[(size_t)(r0 + rr) * DM + h * DH + cc] = oacc;
    }
}

extern "C" void kernel_launch(void* const* d_in, const int* in_sizes, int n_in,
                              void* d_out, int out_size, void* d_ws, size_t ws_size,
                              hipStream_t stream) {
    const float* F  = (const float*)d_in[0];
    const int* bidx = (const int*)d_in[1];
    const float* y  = (const float*)d_in[2];
    const float* Wq = (const float*)d_in[3];
    const float* bq = (const float*)d_in[4];
    const float* Wk = (const float*)d_in[5];
    const float* bk = (const float*)d_in[6];
    const float* Wv = (const float*)d_in[7];
    const float* bv = (const float*)d_in[8];
    const float* Wo = (const float*)d_in[9];
    const float* bo = (const float*)d_in[10];
    const float* lg = (const float*)d_in[11];
    const float* lb = (const float*)d_in[12];
    float* out = (float*)d_out;

    float* ws   = (float*)d_ws;
    float* q_in = ws;                              // NP*DM
    float* qb   = q_in + (size_t)NP * DM;          // NP*DM  (q, later reused for attn-out)
    float* Kp   = qb + (size_t)NP * DM;            // NB*MC*DM
    float* Vp   = Kp + (size_t)NB * MC * DM;       // NB*MC*DM
    float* ob   = Vp + (size_t)NB * MC * DM;       // NP*DM
    int* starts = (int*)(ob + (size_t)NP * DM);    // NB+1

    k_starts<<<1, 64, 0, stream>>>(bidx, starts);
    k_ln<<<NP, 256, 0, stream>>>(F, nullptr, lg, lb, q_in);
    k_gemm_bt<<<dim3(DM / 64, NP / 64), 256, 0, stream>>>(q_in, Wq, bq, qb, DM, DM);
    k_gemm_bt<<<dim3(DM / 64, (NB * MC) / 64), 256, 0, stream>>>(y, Wk, bk, Kp, KVD, DM);
    k_gemm_bt<<<dim3(DM / 64, (NB * MC) / 64), 256, 0, stream>>>(y, Wv, bv, Vp, KVD, DM);
    k_attn<<<dim3((NP + RT - 1) / RT, NB), 256, 0, stream>>>(qb, Kp, Vp, starts, ob);
    k_gemm_bt<<<dim3(DM / 64, NP / 64), 256, 0, stream>>>(ob, Wo, bo, qb, DM, DM);
    k_ln<<<NP, 256, 0, stream>>>(q_in, qb, lg, lb, out);
}

// Round 2
// 236.143 us; speedup vs baseline: 5.2639x; 5.2639x over previous
//
#include <hip/hip_runtime.h>

constexpr int NP = 12288;   // N points
constexpr int NB = 4;       // batches
constexpr int MC = 1024;    // M context
constexpr int DM = 256;     // D
constexpr int KVD = 512;    // KV feature dim
constexpr int NH = 8;       // heads
constexpr int DH = 32;      // head dim

typedef __bf16 bf16x8 __attribute__((ext_vector_type(8)));
typedef __bf16 bf16x4 __attribute__((ext_vector_type(4)));
typedef __bf16 bf16x2 __attribute__((ext_vector_type(2)));
typedef float f32x4v __attribute__((ext_vector_type(4)));

// starts[b] = lower_bound(batch_idx, b); starts[NB] = NP
__global__ void k_starts(const int* __restrict__ bidx, int* __restrict__ starts) {
    int b = threadIdx.x;
    if (b > NB) return;
    int lo = 0, hi = NP;
    while (lo < hi) { int mid = (lo + hi) >> 1; if (bidx[mid] < b) lo = mid + 1; else hi = mid; }
    starts[b] = lo;
}

// y = LN(x [+ x2]) * g + b   ; one row (DM=256) per block, 256 threads
__global__ __launch_bounds__(256) void k_ln(const float* __restrict__ x,
        const float* __restrict__ x2, const float* __restrict__ g,
        const float* __restrict__ bb, float* __restrict__ y) {
    int row = blockIdx.x, t = threadIdx.x;
    float v = x[row * DM + t];
    if (x2) v += x2[row * DM + t];
    __shared__ float red[4];
    float s = v;
#pragma unroll
    for (int o = 1; o < 64; o <<= 1) s += __shfl_xor(s, o);
    if ((t & 63) == 0) red[t >> 6] = s;
    __syncthreads();
    float mu = (red[0] + red[1] + red[2] + red[3]) * (1.0f / DM);
    __syncthreads();
    float dv = v - mu;
    s = dv * dv;
#pragma unroll
    for (int o = 1; o < 64; o <<= 1) s += __shfl_xor(s, o);
    if ((t & 63) == 0) red[t >> 6] = s;
    __syncthreads();
    float var = (red[0] + red[1] + red[2] + red[3]) * (1.0f / DM);
    y[row * DM + t] = dv * rsqrtf(var + 1e-5f) * g[t] + bb[t];
}

// C[r,c] = sum_k A[r,k] * W[c,k] + bias[c]   (fp32, 64x64 tile)
__global__ __launch_bounds__(256) void k_gemm_bt(const float* __restrict__ A,
        const float* __restrict__ W, const float* __restrict__ bias,
        float* __restrict__ C, int K, int Nc) {
    __shared__ float As[64][17];
    __shared__ float Bs[64][17];
    int t = threadIdx.x;
    int tx = t & 15, ty = t >> 4;
    int row0 = blockIdx.y * 64, col0 = blockIdx.x * 64;
    float acc[4][4] = {};
    int lr = t >> 4, lc = t & 15;
    for (int k0 = 0; k0 < K; k0 += 16) {
#pragma unroll
        for (int j = 0; j < 4; ++j) {
            As[lr + j * 16][lc] = A[(size_t)(row0 + lr + j * 16) * K + k0 + lc];
            Bs[lr + j * 16][lc] = W[(size_t)(col0 + lr + j * 16) * K + k0 + lc];
        }
        __syncthreads();
#pragma unroll
        for (int kk = 0; kk < 16; ++kk) {
            float a[4], b[4];
#pragma unroll
            for (int i = 0; i < 4; ++i) a[i] = As[ty * 4 + i][kk];
#pragma unroll
            for (int j = 0; j < 4; ++j) b[j] = Bs[tx * 4 + j][kk];
#pragma unroll
            for (int i = 0; i < 4; ++i)
#pragma unroll
                for (int j = 0; j < 4; ++j) acc[i][j] += a[i] * b[j];
        }
        __syncthreads();
    }
#pragma unroll
    for (int i = 0; i < 4; ++i)
#pragma unroll
        for (int j = 0; j < 4; ++j) {
            int c = col0 + tx * 4 + j;
            C[(size_t)(row0 + ty * 4 + i) * Nc + c] = acc[i][j] + bias[c];
        }
}

// Flash cross-attention, bf16 MFMA 16x16x32.
// Block = (batch b, head h, 64-row q-tile). 4 waves; wave w owns q-rows [16w,16w+16).
// Swapped QK^T: S^T = mfma(A=K_tile, B=Q) so each lane holds scores of ONE q-row.
__global__ __launch_bounds__(256) void k_attn_mfma(const float* __restrict__ q,
        const float* __restrict__ Kc, const float* __restrict__ Vc,
        const int* __restrict__ starts, float* __restrict__ o) {
    const int b = blockIdx.z, h = blockIdx.y;
    const int r0 = starts[b] + blockIdx.x * 64;
    const int rend = starts[b + 1];
    if (r0 >= rend) return;
    const int nr = min(64, rend - r0);

    __shared__ __bf16 Ks[64][36];   // [m][dh], stride 36 -> conflict-free 16-row reads
    __shared__ __bf16 Vt[32][76];   // [dh][m] transposed, stride 76

    const int t = threadIdx.x;
    const int w = t >> 6, l = t & 63;
    const int lg = l >> 4, ln = l & 15;

    const float* Kb = Kc + (size_t)b * MC * DM + h * DH;
    const float* Vb = Vc + (size_t)b * MC * DM + h * DH;
    const float scale = 0.17677669529663687f;  // 1/sqrt(32)

    // Q B-fragment (n = q-row = ln, k = 4*lg+j and 16+4*lg+j), scale folded in.
    const int qr = min(r0 + w * 16 + ln, NP - 1);
    const float* qp = q + (size_t)qr * DM + h * DH + lg * 4;
    float4 q0 = *(const float4*)qp;
    float4 q1 = *(const float4*)(qp + 16);
    bf16x8 qf;
    qf[0] = (__bf16)(q0.x * scale); qf[1] = (__bf16)(q0.y * scale);
    qf[2] = (__bf16)(q0.z * scale); qf[3] = (__bf16)(q0.w * scale);
    qf[4] = (__bf16)(q1.x * scale); qf[5] = (__bf16)(q1.y * scale);
    qf[6] = (__bf16)(q1.z * scale); qf[7] = (__bf16)(q1.w * scale);

    f32x4v Oacc[2] = {{0.f, 0.f, 0.f, 0.f}, {0.f, 0.f, 0.f, 0.f}};
    float mrun = -1e30f, lrun = 0.f;

    // staging indices
    const int krow = t >> 3, kq = t & 7;       // K: (row, dh-quad), 2 rows per thread
    const int vq = t >> 5, vmp = t & 31;       // V: (dh-quad, m-pair)

    for (int mt = 0; mt < MC / 64; ++mt) {
        const int m0 = mt * 64;
        // global loads (fp32)
        float4 kv0 = *(const float4*)&Kb[(size_t)(m0 + krow) * DM + kq * 4];
        float4 kv1 = *(const float4*)&Kb[(size_t)(m0 + 32 + krow) * DM + kq * 4];
        float4 va  = *(const float4*)&Vb[(size_t)(m0 + 2 * vmp) * DM + vq * 4];
        float4 vb2 = *(const float4*)&Vb[(size_t)(m0 + 2 * vmp + 1) * DM + vq * 4];
        __syncthreads();   // prior iter's readers done
        {
            bf16x4 a, c;
            a[0] = (__bf16)kv0.x; a[1] = (__bf16)kv0.y; a[2] = (__bf16)kv0.z; a[3] = (__bf16)kv0.w;
            c[0] = (__bf16)kv1.x; c[1] = (__bf16)kv1.y; c[2] = (__bf16)kv1.z; c[3] = (__bf16)kv1.w;
            *(bf16x4*)&Ks[krow][kq * 4] = a;
            *(bf16x4*)&Ks[32 + krow][kq * 4] = c;
            float fa[4] = {va.x, va.y, va.z, va.w};
            float fb[4] = {vb2.x, vb2.y, vb2.z, vb2.w};
#pragma unroll
            for (int k = 0; k < 4; ++k) {
                bf16x2 p2; p2[0] = (__bf16)fa[k]; p2[1] = (__bf16)fb[k];
                *(bf16x2*)&Vt[vq * 4 + k][2 * vmp] = p2;
            }
        }
        __syncthreads();

        // ---- QK^T (swapped): S[ms][r] = score(q-row=ln, m = m0 + ms*16 + 4*lg + r)
        f32x4v S[4];
#pragma unroll
        for (int ms = 0; ms < 4; ++ms) {
            bf16x4 lo = *(const bf16x4*)&Ks[ms * 16 + ln][lg * 4];
            bf16x4 hi = *(const bf16x4*)&Ks[ms * 16 + ln][16 + lg * 4];
            bf16x8 kf = __builtin_shufflevector(lo, hi, 0, 1, 2, 3, 4, 5, 6, 7);
            S[ms] = __builtin_amdgcn_mfma_f32_16x16x32_bf16(
                kf, qf, (f32x4v){0.f, 0.f, 0.f, 0.f}, 0, 0, 0);
        }
        // ---- online softmax (row = ln; 4 group-copies reduced via shfl)
        float tmax = -1e30f;
#pragma unroll
        for (int ms = 0; ms < 4; ++ms)
#pragma unroll
            for (int r = 0; r < 4; ++r) tmax = fmaxf(tmax, S[ms][r]);
        tmax = fmaxf(tmax, __shfl_xor(tmax, 16));
        tmax = fmaxf(tmax, __shfl_xor(tmax, 32));
        float newm = fmaxf(mrun, tmax);
        float corr = __expf(mrun - newm);
        float pv[16]; float psum = 0.f;
#pragma unroll
        for (int ms = 0; ms < 4; ++ms)
#pragma unroll
            for (int r = 0; r < 4; ++r) {
                float e = __expf(S[ms][r] - newm);
                pv[ms * 4 + r] = e; psum += e;
            }
        psum += __shfl_xor(psum, 16);
        psum += __shfl_xor(psum, 32);
        lrun = lrun * corr + psum; mrun = newm;
        // O-acc rows are 4*lg+reg -> fetch that row's corr
        float c4[4];
#pragma unroll
        for (int r = 0; r < 4; ++r) c4[r] = __shfl(corr, 4 * lg + r);
#pragma unroll
        for (int r = 0; r < 4; ++r) { Oacc[0][r] *= c4[r]; Oacc[1][r] *= c4[r]; }
        // P fragments (A-operand layout falls out of swapped-QK directly)
        bf16x8 pa0, pa1;
#pragma unroll
        for (int j = 0; j < 8; ++j) { pa0[j] = (__bf16)pv[j]; pa1[j] = (__bf16)pv[8 + j]; }
        // ---- PV: Oacc[nt] += P[:, mh*32..] @ V[mh*32.., nt*16..]
#pragma unroll
        for (int mh = 0; mh < 2; ++mh) {
            bf16x8 pf = mh ? pa1 : pa0;
#pragma unroll
            for (int nt = 0; nt < 2; ++nt) {
                bf16x4 lo = *(const bf16x4*)&Vt[nt * 16 + ln][mh * 32 + lg * 4];
                bf16x4 hi = *(const bf16x4*)&Vt[nt * 16 + ln][mh * 32 + 16 + lg * 4];
                bf16x8 vf = __builtin_shufflevector(lo, hi, 0, 1, 2, 3, 4, 5, 6, 7);
                Oacc[nt] = __builtin_amdgcn_mfma_f32_16x16x32_bf16(pf, vf, Oacc[nt], 0, 0, 0);
            }
        }
    }
    // epilogue: divide by lrun, write rows 4*lg+r of this wave's 16-row tile
    float inv = 1.0f / lrun;
    float iv[4];
#pragma unroll
    for (int r = 0; r < 4; ++r) iv[r] = __shfl(inv, 4 * lg + r);
#pragma unroll
    for (int r = 0; r < 4; ++r) {
        int rloc = w * 16 + 4 * lg + r;
        if (rloc < nr) {
            size_t base = (size_t)(r0 + rloc) * DM + h * DH + ln;
            o[base] = Oacc[0][r] * iv[r];
            o[base + 16] = Oacc[1][r] * iv[r];
        }
    }
}

extern "C" void kernel_launch(void* const* d_in, const int* in_sizes, int n_in,
                              void* d_out, int out_size, void* d_ws, size_t ws_size,
                              hipStream_t stream) {
    const float* F  = (const float*)d_in[0];
    const int* bidx = (const int*)d_in[1];
    const float* y  = (const float*)d_in[2];
    const float* Wq = (const float*)d_in[3];
    const float* bq = (const float*)d_in[4];
    const float* Wk = (const float*)d_in[5];
    const float* bk = (const float*)d_in[6];
    const float* Wv = (const float*)d_in[7];
    const float* bv = (const float*)d_in[8];
    const float* Wo = (const float*)d_in[9];
    const float* bo = (const float*)d_in[10];
    const float* lg = (const float*)d_in[11];
    const float* lb = (const float*)d_in[12];
    float* out = (float*)d_out;

    float* ws   = (float*)d_ws;
    float* q_in = ws;                              // NP*DM
    float* qb   = q_in + (size_t)NP * DM;          // NP*DM
    float* Kp   = qb + (size_t)NP * DM;            // NB*MC*DM
    float* Vp   = Kp + (size_t)NB * MC * DM;       // NB*MC*DM
    float* ob   = Vp + (size_t)NB * MC * DM;       // NP*DM
    int* starts = (int*)(ob + (size_t)NP * DM);    // NB+1

    k_starts<<<1, 64, 0, stream>>>(bidx, starts);
    k_ln<<<NP, 256, 0, stream>>>(F, nullptr, lg, lb, q_in);
    k_gemm_bt<<<dim3(DM / 64, NP / 64), 256, 0, stream>>>(q_in, Wq, bq, qb, DM, DM);
    k_gemm_bt<<<dim3(DM / 64, (NB * MC) / 64), 256, 0, stream>>>(y, Wk, bk, Kp, KVD, DM);
    k_gemm_bt<<<dim3(DM / 64, (NB * MC) / 64), 256, 0, stream>>>(y, Wv, bv, Vp, KVD, DM);
    k_attn_mfma<<<dim3(NP / 64, NH, NB), 256, 0, stream>>>(qb, Kp, Vp, starts, ob);
    k_gemm_bt<<<dim3(DM / 64, NP / 64), 256, 0, stream>>>(ob, Wo, bo, qb, DM, DM);
    k_ln<<<NP, 256, 0, stream>>>(q_in, qb, lg, lb, out);
}

// Round 3
// 128.660 us; speedup vs baseline: 9.6613x; 1.8354x over previous
//
#include <hip/hip_runtime.h>

constexpr int NP = 12288;   // N points
constexpr int NB = 4;       // batches
constexpr int MC = 1024;    // M context
constexpr int DM = 256;     // D
constexpr int KVD = 512;    // KV feature dim
constexpr int NH = 8;       // heads
constexpr int DH = 32;      // head dim

typedef __bf16 bf16x8 __attribute__((ext_vector_type(8)));
typedef __bf16 bf16x4 __attribute__((ext_vector_type(4)));
typedef float f32x4v __attribute__((ext_vector_type(4)));

// starts[b] = lower_bound(batch_idx, b); starts[NB] = NP
__global__ void k_starts(const int* __restrict__ bidx, int* __restrict__ starts) {
    int b = threadIdx.x;
    if (b > NB) return;
    int lo = 0, hi = NP;
    while (lo < hi) { int mid = (lo + hi) >> 1; if (bidx[mid] < b) lo = mid + 1; else hi = mid; }
    starts[b] = lo;
}

// fp32 -> bf16 for y + 4 weight matrices (compile-time segment table)
__global__ __launch_bounds__(256) void k_conv(const float* __restrict__ y,
        const float* __restrict__ wq, const float* __restrict__ wk,
        const float* __restrict__ wv, const float* __restrict__ wo,
        __bf16* yb, __bf16* wqb, __bf16* wkb, __bf16* wvb, __bf16* wob) {
    size_t i = ((size_t)blockIdx.x * 256 + threadIdx.x) * 4;
    const float* s; __bf16* d; size_t off;
    if      (i < 2097152) { s = y;  d = yb;  off = 0; }
    else if (i < 2162688) { s = wq; d = wqb; off = 2097152; }
    else if (i < 2293760) { s = wk; d = wkb; off = 2162688; }
    else if (i < 2424832) { s = wv; d = wvb; off = 2293760; }
    else if (i < 2490368) { s = wo; d = wob; off = 2424832; }
    else return;
    size_t j = i - off;
    float4 v = *(const float4*)&s[j];
    bf16x4 o; o[0] = (__bf16)v.x; o[1] = (__bf16)v.y; o[2] = (__bf16)v.z; o[3] = (__bf16)v.w;
    *(bf16x4*)&d[j] = o;
}

// LayerNorm, wave-per-row (4 rows/block). Optional second input (residual),
// optional bf16 copy of the output.
__global__ __launch_bounds__(256) void k_ln4(const float* __restrict__ x,
        const float* __restrict__ x2, const float* __restrict__ g,
        const float* __restrict__ bb, float* __restrict__ yout,
        __bf16* __restrict__ yb) {
    int t = threadIdx.x, w = t >> 6, l = t & 63;
    size_t row = (size_t)blockIdx.x * 4 + w;
    float4 v = *(const float4*)&x[row * DM + l * 4];
    if (x2) {
        float4 a = *(const float4*)&x2[row * DM + l * 4];
        v.x += a.x; v.y += a.y; v.z += a.z; v.w += a.w;
    }
    float s = v.x + v.y + v.z + v.w;
#pragma unroll
    for (int o2 = 1; o2 < 64; o2 <<= 1) s += __shfl_xor(s, o2);
    float mu = s * (1.f / DM);
    float4 d = {v.x - mu, v.y - mu, v.z - mu, v.w - mu};
    float ss = d.x * d.x + d.y * d.y + d.z * d.z + d.w * d.w;
#pragma unroll
    for (int o2 = 1; o2 < 64; o2 <<= 1) ss += __shfl_xor(ss, o2);
    float rr = rsqrtf(ss * (1.f / DM) + 1e-5f);
    float4 gg = *(const float4*)&g[l * 4];
    float4 bv = *(const float4*)&bb[l * 4];
    float4 o4 = {d.x * rr * gg.x + bv.x, d.y * rr * gg.y + bv.y,
                 d.z * rr * gg.z + bv.z, d.w * rr * gg.w + bv.w};
    *(float4*)&yout[row * DM + l * 4] = o4;
    if (yb) {
        bf16x4 ob4; ob4[0] = (__bf16)o4.x; ob4[1] = (__bf16)o4.y;
        ob4[2] = (__bf16)o4.z; ob4[3] = (__bf16)o4.w;
        *(bf16x4*)&yb[row * DM + l * 4] = ob4;
    }
}

// bf16 MFMA GEMM: C[r,c] = sum_k A[r,k]*W[c,k] + bias[c], C is [M][256].
// Tile 128x64, BK=64, 4 waves (2x2), 16x16x32 MFMA. Output fp32 (Cf) or bf16 (Cb).
__global__ __launch_bounds__(256) void k_gemm_mfma(const __bf16* __restrict__ A,
        const __bf16* __restrict__ W, const float* __restrict__ bias,
        float* __restrict__ Cf, __bf16* __restrict__ Cb, int K) {
    __shared__ __bf16 As[128][72];   // stride 72 -> 2-way bank alias (free)
    __shared__ __bf16 Bs[64][72];
    const int t = threadIdx.x;
    const int w = t >> 6, l = t & 63, lg = l >> 4, ln = l & 15;
    const int wr = w >> 1, wc = w & 1;
    const int row0 = blockIdx.y * 128, col0 = blockIdx.x * 64;
    const int ar = t >> 3, ac8 = (t & 7) * 8;   // staging: 32 rows/pass, 8 cols of 8
    f32x4v acc[4][2] = {};
    for (int k0 = 0; k0 < K; k0 += 64) {
        bf16x8 a0 = *(const bf16x8*)&A[(size_t)(row0 + ar) * K + k0 + ac8];
        bf16x8 a1 = *(const bf16x8*)&A[(size_t)(row0 + ar + 32) * K + k0 + ac8];
        bf16x8 a2 = *(const bf16x8*)&A[(size_t)(row0 + ar + 64) * K + k0 + ac8];
        bf16x8 a3 = *(const bf16x8*)&A[(size_t)(row0 + ar + 96) * K + k0 + ac8];
        bf16x8 b0 = *(const bf16x8*)&W[(size_t)(col0 + ar) * K + k0 + ac8];
        bf16x8 b1 = *(const bf16x8*)&W[(size_t)(col0 + ar + 32) * K + k0 + ac8];
        __syncthreads();
        *(bf16x8*)&As[ar][ac8] = a0;
        *(bf16x8*)&As[ar + 32][ac8] = a1;
        *(bf16x8*)&As[ar + 64][ac8] = a2;
        *(bf16x8*)&As[ar + 96][ac8] = a3;
        *(bf16x8*)&Bs[ar][ac8] = b0;
        *(bf16x8*)&Bs[ar + 32][ac8] = b1;
        __syncthreads();
#pragma unroll
        for (int kk = 0; kk < 2; ++kk) {
            bf16x8 bfr[2];
#pragma unroll
            for (int ni = 0; ni < 2; ++ni) {
                bf16x4 lo = *(const bf16x4*)&Bs[wc * 32 + ni * 16 + ln][kk * 32 + lg * 4];
                bf16x4 hi = *(const bf16x4*)&Bs[wc * 32 + ni * 16 + ln][kk * 32 + 16 + lg * 4];
                bfr[ni] = __builtin_shufflevector(lo, hi, 0, 1, 2, 3, 4, 5, 6, 7);
            }
#pragma unroll
            for (int mi = 0; mi < 4; ++mi) {
                bf16x4 lo = *(const bf16x4*)&As[wr * 64 + mi * 16 + ln][kk * 32 + lg * 4];
                bf16x4 hi = *(const bf16x4*)&As[wr * 64 + mi * 16 + ln][kk * 32 + 16 + lg * 4];
                bf16x8 af = __builtin_shufflevector(lo, hi, 0, 1, 2, 3, 4, 5, 6, 7);
#pragma unroll
                for (int ni = 0; ni < 2; ++ni)
                    acc[mi][ni] = __builtin_amdgcn_mfma_f32_16x16x32_bf16(af, bfr[ni], acc[mi][ni], 0, 0, 0);
            }
        }
    }
#pragma unroll
    for (int mi = 0; mi < 4; ++mi)
#pragma unroll
        for (int ni = 0; ni < 2; ++ni) {
            int col = col0 + wc * 32 + ni * 16 + ln;
            float bv = bias[col];
#pragma unroll
            for (int r = 0; r < 4; ++r) {
                size_t row = (size_t)(row0 + wr * 64 + mi * 16 + 4 * lg + r);
                float val = acc[mi][ni][r] + bv;
                if (Cf) Cf[row * DM + col] = val;
                else    Cb[row * DM + col] = (__bf16)val;
            }
        }
}

// Flash cross-attention, bf16 in/out, MFMA 16x16x32.
// Block = (64-row q-tile, head, batch); 4 waves; wave w owns q-rows [16w,16w+16).
__global__ __launch_bounds__(256) void k_attn_mfma(const __bf16* __restrict__ q,
        const __bf16* __restrict__ Kc, const __bf16* __restrict__ Vc,
        const int* __restrict__ starts, __bf16* __restrict__ o) {
    const int b = blockIdx.z, h = blockIdx.y;
    const int r0 = starts[b] + blockIdx.x * 64;
    const int rend = starts[b + 1];
    if (r0 >= rend) return;
    const int nr = min(64, rend - r0);

    __shared__ __bf16 Ks[64][40];   // [m][dh], stride 40 -> 2-way alias (free)
    __shared__ __bf16 Vt[32][72];   // [dh][m] transposed

    const int t = threadIdx.x;
    const int w = t >> 6, l = t & 63, lg = l >> 4, ln = l & 15;

    const __bf16* Kb = Kc + (size_t)b * MC * DM + h * DH;
    const __bf16* Vb = Vc + (size_t)b * MC * DM + h * DH;
    const float scale = 0.17677669529663687f;  // 1/sqrt(32)

    // Q B-fragment (n = q-row = ln, k = 4*lg+j | 16+4*lg+j)
    const int qr = min(r0 + w * 16 + ln, NP - 1);
    const __bf16* qp = q + (size_t)qr * DM + h * DH;
    bf16x4 qlo = *(const bf16x4*)(qp + lg * 4);
    bf16x4 qhi = *(const bf16x4*)(qp + 16 + lg * 4);
    bf16x8 qf = __builtin_shufflevector(qlo, qhi, 0, 1, 2, 3, 4, 5, 6, 7);

    f32x4v Oacc[2] = {{0.f, 0.f, 0.f, 0.f}, {0.f, 0.f, 0.f, 0.f}};
    float mrun = -1e30f, lrun = 0.f;

    const int krow = t >> 2, kc8 = (t & 3) * 8;  // K staging: row, 8-col chunk
    const int vm = t & 63, vd0 = (t >> 6) * 8;   // V staging: m, 8 d-elems

    for (int mt = 0; mt < MC / 64; ++mt) {
        const int m0 = mt * 64;
        bf16x8 kv = *(const bf16x8*)&Kb[(size_t)(m0 + krow) * DM + kc8];
        bf16x8 vv = *(const bf16x8*)&Vb[(size_t)(m0 + vm) * DM + vd0];
        __syncthreads();   // prior iter's readers done
        *(bf16x8*)&Ks[krow][kc8] = kv;
#pragma unroll
        for (int j = 0; j < 8; ++j) Vt[vd0 + j][vm] = vv[j];
        __syncthreads();

        // ---- QK^T (swapped): S[ms][r] = score(q-row=ln, m = m0 + ms*16 + 4*lg + r)
        f32x4v S[4];
#pragma unroll
        for (int ms = 0; ms < 4; ++ms) {
            bf16x4 lo = *(const bf16x4*)&Ks[ms * 16 + ln][lg * 4];
            bf16x4 hi = *(const bf16x4*)&Ks[ms * 16 + ln][16 + lg * 4];
            bf16x8 kf = __builtin_shufflevector(lo, hi, 0, 1, 2, 3, 4, 5, 6, 7);
            S[ms] = __builtin_amdgcn_mfma_f32_16x16x32_bf16(
                kf, qf, (f32x4v){0.f, 0.f, 0.f, 0.f}, 0, 0, 0);
#pragma unroll
            for (int r = 0; r < 4; ++r) S[ms][r] *= scale;
        }
        // ---- online softmax (row = ln; 4 group-copies reduced via shfl)
        float tmax = -1e30f;
#pragma unroll
        for (int ms = 0; ms < 4; ++ms)
#pragma unroll
            for (int r = 0; r < 4; ++r) tmax = fmaxf(tmax, S[ms][r]);
        tmax = fmaxf(tmax, __shfl_xor(tmax, 16));
        tmax = fmaxf(tmax, __shfl_xor(tmax, 32));
        float newm = fmaxf(mrun, tmax);
        float corr = __expf(mrun - newm);
        float pv[16]; float psum = 0.f;
#pragma unroll
        for (int ms = 0; ms < 4; ++ms)
#pragma unroll
            for (int r = 0; r < 4; ++r) {
                float e = __expf(S[ms][r] - newm);
                pv[ms * 4 + r] = e; psum += e;
            }
        psum += __shfl_xor(psum, 16);
        psum += __shfl_xor(psum, 32);
        lrun = lrun * corr + psum; mrun = newm;
        float c4[4];
#pragma unroll
        for (int r = 0; r < 4; ++r) c4[r] = __shfl(corr, 4 * lg + r);
#pragma unroll
        for (int r = 0; r < 4; ++r) { Oacc[0][r] *= c4[r]; Oacc[1][r] *= c4[r]; }
        bf16x8 pa0, pa1;
#pragma unroll
        for (int j = 0; j < 8; ++j) { pa0[j] = (__bf16)pv[j]; pa1[j] = (__bf16)pv[8 + j]; }
        // ---- PV
#pragma unroll
        for (int mh = 0; mh < 2; ++mh) {
            bf16x8 pf = mh ? pa1 : pa0;
#pragma unroll
            for (int nt = 0; nt < 2; ++nt) {
                bf16x4 lo = *(const bf16x4*)&Vt[nt * 16 + ln][mh * 32 + lg * 4];
                bf16x4 hi = *(const bf16x4*)&Vt[nt * 16 + ln][mh * 32 + 16 + lg * 4];
                bf16x8 vf = __builtin_shufflevector(lo, hi, 0, 1, 2, 3, 4, 5, 6, 7);
                Oacc[nt] = __builtin_amdgcn_mfma_f32_16x16x32_bf16(pf, vf, Oacc[nt], 0, 0, 0);
            }
        }
    }
    // epilogue
    float inv = 1.0f / lrun;
    float iv[4];
#pragma unroll
    for (int r = 0; r < 4; ++r) iv[r] = __shfl(inv, 4 * lg + r);
#pragma unroll
    for (int r = 0; r < 4; ++r) {
        int rloc = w * 16 + 4 * lg + r;
        if (rloc < nr) {
            size_t base = (size_t)(r0 + rloc) * DM + h * DH + ln;
            o[base] = (__bf16)(Oacc[0][r] * iv[r]);
            o[base + 16] = (__bf16)(Oacc[1][r] * iv[r]);
        }
    }
}

extern "C" void kernel_launch(void* const* d_in, const int* in_sizes, int n_in,
                              void* d_out, int out_size, void* d_ws, size_t ws_size,
                              hipStream_t stream) {
    const float* F  = (const float*)d_in[0];
    const int* bidx = (const int*)d_in[1];
    const float* y  = (const float*)d_in[2];
    const float* Wq = (const float*)d_in[3];
    const float* bq = (const float*)d_in[4];
    const float* Wk = (const float*)d_in[5];
    const float* bk = (const float*)d_in[6];
    const float* Wv = (const float*)d_in[7];
    const float* bv = (const float*)d_in[8];
    const float* Wo = (const float*)d_in[9];
    const float* bo = (const float*)d_in[10];
    const float* lg = (const float*)d_in[11];
    const float* lb = (const float*)d_in[12];
    float* out = (float*)d_out;

    char* ws = (char*)d_ws;
    float* q_in = (float*)ws;                    ws += (size_t)NP * DM * 4;   // fp32
    float* attn = (float*)ws;                    ws += (size_t)NP * DM * 4;   // fp32
    __bf16* q_in_b = (__bf16*)ws;                ws += (size_t)NP * DM * 2;
    __bf16* qb     = (__bf16*)ws;                ws += (size_t)NP * DM * 2;
    __bf16* ob     = (__bf16*)ws;                ws += (size_t)NP * DM * 2;
    __bf16* y_b    = (__bf16*)ws;                ws += (size_t)NB * MC * KVD * 2;
    __bf16* Kp     = (__bf16*)ws;                ws += (size_t)NB * MC * DM * 2;
    __bf16* Vp     = (__bf16*)ws;                ws += (size_t)NB * MC * DM * 2;
    __bf16* Wq_b   = (__bf16*)ws;                ws += (size_t)DM * DM * 2;
    __bf16* Wk_b   = (__bf16*)ws;                ws += (size_t)DM * KVD * 2;
    __bf16* Wv_b   = (__bf16*)ws;                ws += (size_t)DM * KVD * 2;
    __bf16* Wo_b   = (__bf16*)ws;                ws += (size_t)DM * DM * 2;
    int* starts    = (int*)ws;

    k_starts<<<1, 64, 0, stream>>>(bidx, starts);
    k_conv<<<2433, 256, 0, stream>>>(y, Wq, Wk, Wv, Wo, y_b, Wq_b, Wk_b, Wv_b, Wo_b);
    k_ln4<<<NP / 4, 256, 0, stream>>>(F, nullptr, lg, lb, q_in, q_in_b);
    k_gemm_mfma<<<dim3(4, NP / 128), 256, 0, stream>>>(q_in_b, Wq_b, bq, nullptr, qb, DM);
    k_gemm_mfma<<<dim3(4, (NB * MC) / 128), 256, 0, stream>>>(y_b, Wk_b, bk, nullptr, Kp, KVD);
    k_gemm_mfma<<<dim3(4, (NB * MC) / 128), 256, 0, stream>>>(y_b, Wv_b, bv, nullptr, Vp, KVD);
    k_attn_mfma<<<dim3(NP / 64, NH, NB), 256, 0, stream>>>(qb, Kp, Vp, starts, ob);
    k_gemm_mfma<<<dim3(4, NP / 128), 256, 0, stream>>>(ob, Wo_b, bo, attn, nullptr, DM);
    k_ln4<<<NP / 4, 256, 0, stream>>>(q_in, attn, lg, lb, out, nullptr);
}

// Round 4
// 96.010 us; speedup vs baseline: 12.9468x; 1.3401x over previous
//
#include <hip/hip_runtime.h>

constexpr int NP = 12288;   // N points
constexpr int NB = 4;       // batches
constexpr int MC = 1024;    // M context
constexpr int DM = 256;     // D
constexpr int KVD = 512;    // KV feature dim
constexpr int NH = 8;       // heads
constexpr int DH = 32;      // head dim

typedef __bf16 bf16x8 __attribute__((ext_vector_type(8)));
typedef __bf16 bf16x4 __attribute__((ext_vector_type(4)));
typedef float f32x4v __attribute__((ext_vector_type(4)));

// starts[b] = lower_bound(batch_idx, b); starts[NB] = NP
__global__ void k_starts(const int* __restrict__ bidx, int* __restrict__ starts) {
    int b = threadIdx.x;
    if (b > NB) return;
    int lo = 0, hi = NP;
    while (lo < hi) { int mid = (lo + hi) >> 1; if (bidx[mid] < b) lo = mid + 1; else hi = mid; }
    starts[b] = lo;
}

// fp32 -> bf16 for y + 4 weight matrices
__global__ __launch_bounds__(256) void k_conv(const float* __restrict__ y,
        const float* __restrict__ wq, const float* __restrict__ wk,
        const float* __restrict__ wv, const float* __restrict__ wo,
        __bf16* yb, __bf16* wqb, __bf16* wkb, __bf16* wvb, __bf16* wob) {
    size_t i = ((size_t)blockIdx.x * 256 + threadIdx.x) * 4;
    const float* s; __bf16* d; size_t off;
    if      (i < 2097152) { s = y;  d = yb;  off = 0; }
    else if (i < 2162688) { s = wq; d = wqb; off = 2097152; }
    else if (i < 2293760) { s = wk; d = wkb; off = 2162688; }
    else if (i < 2424832) { s = wv; d = wvb; off = 2293760; }
    else if (i < 2490368) { s = wo; d = wob; off = 2424832; }
    else return;
    size_t j = i - off;
    float4 v = *(const float4*)&s[j];
    bf16x4 o; o[0] = (__bf16)v.x; o[1] = (__bf16)v.y; o[2] = (__bf16)v.z; o[3] = (__bf16)v.w;
    *(bf16x4*)&d[j] = o;
}

// LayerNorm, wave-per-row (4 rows/block).
__global__ __launch_bounds__(256) void k_ln4(const float* __restrict__ x,
        const float* __restrict__ x2, const float* __restrict__ g,
        const float* __restrict__ bb, float* __restrict__ yout,
        __bf16* __restrict__ yb) {
    int t = threadIdx.x, w = t >> 6, l = t & 63;
    size_t row = (size_t)blockIdx.x * 4 + w;
    float4 v = *(const float4*)&x[row * DM + l * 4];
    if (x2) {
        float4 a = *(const float4*)&x2[row * DM + l * 4];
        v.x += a.x; v.y += a.y; v.z += a.z; v.w += a.w;
    }
    float s = v.x + v.y + v.z + v.w;
#pragma unroll
    for (int o2 = 1; o2 < 64; o2 <<= 1) s += __shfl_xor(s, o2);
    float mu = s * (1.f / DM);
    float4 d = {v.x - mu, v.y - mu, v.z - mu, v.w - mu};
    float ss = d.x * d.x + d.y * d.y + d.z * d.z + d.w * d.w;
#pragma unroll
    for (int o2 = 1; o2 < 64; o2 <<= 1) ss += __shfl_xor(ss, o2);
    float rr = rsqrtf(ss * (1.f / DM) + 1e-5f);
    float4 gg = *(const float4*)&g[l * 4];
    float4 bv = *(const float4*)&bb[l * 4];
    float4 o4 = {d.x * rr * gg.x + bv.x, d.y * rr * gg.y + bv.y,
                 d.z * rr * gg.z + bv.z, d.w * rr * gg.w + bv.w};
    *(float4*)&yout[row * DM + l * 4] = o4;
    if (yb) {
        bf16x4 ob4; ob4[0] = (__bf16)o4.x; ob4[1] = (__bf16)o4.y;
        ob4[2] = (__bf16)o4.z; ob4[3] = (__bf16)o4.w;
        *(bf16x4*)&yb[row * DM + l * 4] = ob4;
    }
}

// bf16 MFMA GEMM: C[r,c] = (sum_k A[r,k]*W[c,k] + bias[c]) * oscale.
// Tile 128x64, BK=64, 4 waves. Normal path: SWAPPED mfma -> lane holds 4
// consecutive cols -> vector stores (fp32 Cf or bf16 Cb, [row][256]).
// If W2 != null: blocks with bx >= gridDim.x/2 compute A@W2^T+bias2 and write
// TRANSPOSED per batch: CbT[b][col][m] (normal mfma -> 4 consecutive m/lane).
__global__ __launch_bounds__(256) void k_gemm(const __bf16* __restrict__ A,
        const __bf16* __restrict__ W, const float* __restrict__ bias,
        const __bf16* __restrict__ W2, const float* __restrict__ bias2,
        float* __restrict__ Cf, __bf16* __restrict__ Cb, __bf16* __restrict__ CbT,
        int K, float oscale) {
    __shared__ __bf16 As[128][68];   // 34 words/row, ≡2 mod 4 -> 1-way frag reads
    __shared__ __bf16 Bs[64][68];
    const int t = threadIdx.x;
    const int w = t >> 6, l = t & 63, lg = l >> 4, ln = l & 15;
    const int wr = w >> 1, wc = w & 1;
    const int row0 = blockIdx.y * 128;
    bool vpath = false;
    int col0 = blockIdx.x * 64;
    const __bf16* Wm = W; const float* bi = bias;
    if (W2) {
        int half = gridDim.x >> 1;
        if ((int)blockIdx.x >= half) {
            vpath = true; Wm = W2; bi = bias2; col0 = (blockIdx.x - half) * 64;
        }
    }
    const int ar = t >> 3, ac8 = (t & 7) * 8;
    f32x4v acc[4][2] = {};
    bf16x8 ra0, ra1, ra2, ra3, rb0, rb1;
#define LOADG(K0) \
    ra0 = *(const bf16x8*)&A[(size_t)(row0 + ar) * K + (K0) + ac8];        \
    ra1 = *(const bf16x8*)&A[(size_t)(row0 + ar + 32) * K + (K0) + ac8];   \
    ra2 = *(const bf16x8*)&A[(size_t)(row0 + ar + 64) * K + (K0) + ac8];   \
    ra3 = *(const bf16x8*)&A[(size_t)(row0 + ar + 96) * K + (K0) + ac8];   \
    rb0 = *(const bf16x8*)&Wm[(size_t)(col0 + ar) * K + (K0) + ac8];       \
    rb1 = *(const bf16x8*)&Wm[(size_t)(col0 + ar + 32) * K + (K0) + ac8];
    LOADG(0)
    for (int k0 = 0; k0 < K; k0 += 64) {
        __syncthreads();
        *(bf16x8*)&As[ar][ac8] = ra0;
        *(bf16x8*)&As[ar + 32][ac8] = ra1;
        *(bf16x8*)&As[ar + 64][ac8] = ra2;
        *(bf16x8*)&As[ar + 96][ac8] = ra3;
        *(bf16x8*)&Bs[ar][ac8] = rb0;
        *(bf16x8*)&Bs[ar + 32][ac8] = rb1;
        __syncthreads();
        if (k0 + 64 < K) { LOADG(k0 + 64) }
#pragma unroll
        for (int kk = 0; kk < 2; ++kk) {
            bf16x8 bfr[2];
#pragma unroll
            for (int ni = 0; ni < 2; ++ni) {
                bf16x4 lo = *(const bf16x4*)&Bs[wc * 32 + ni * 16 + ln][kk * 32 + lg * 4];
                bf16x4 hi = *(const bf16x4*)&Bs[wc * 32 + ni * 16 + ln][kk * 32 + 16 + lg * 4];
                bfr[ni] = __builtin_shufflevector(lo, hi, 0, 1, 2, 3, 4, 5, 6, 7);
            }
#pragma unroll
            for (int mi = 0; mi < 4; ++mi) {
                bf16x4 lo = *(const bf16x4*)&As[wr * 64 + mi * 16 + ln][kk * 32 + lg * 4];
                bf16x4 hi = *(const bf16x4*)&As[wr * 64 + mi * 16 + ln][kk * 32 + 16 + lg * 4];
                bf16x8 af = __builtin_shufflevector(lo, hi, 0, 1, 2, 3, 4, 5, 6, 7);
#pragma unroll
                for (int ni = 0; ni < 2; ++ni) {
                    if (vpath)
                        acc[mi][ni] = __builtin_amdgcn_mfma_f32_16x16x32_bf16(af, bfr[ni], acc[mi][ni], 0, 0, 0);
                    else
                        acc[mi][ni] = __builtin_amdgcn_mfma_f32_16x16x32_bf16(bfr[ni], af, acc[mi][ni], 0, 0, 0);
                }
            }
        }
    }
#undef LOADG
    if (vpath) {
        // lane: col (V^T row) = col0+wc*32+ni*16+ln; 4 consecutive m per reg
#pragma unroll
        for (int mi = 0; mi < 4; ++mi)
#pragma unroll
            for (int ni = 0; ni < 2; ++ni) {
                int col = col0 + wc * 32 + ni * 16 + ln;
                float bv = bi[col];
                int grow = row0 + wr * 64 + mi * 16 + 4 * lg;  // global A-row
                int b = grow >> 10, m = grow & 1023;
                bf16x4 pk;
#pragma unroll
                for (int r = 0; r < 4; ++r) pk[r] = (__bf16)((acc[mi][ni][r] + bv) * oscale);
                *(bf16x4*)&CbT[((size_t)b * DM + col) * MC + m] = pk;
            }
    } else {
        // lane: row = row0+wr*64+mi*16+ln; 4 consecutive cols per reg
#pragma unroll
        for (int mi = 0; mi < 4; ++mi)
#pragma unroll
            for (int ni = 0; ni < 2; ++ni) {
                int cb = col0 + wc * 32 + ni * 16 + 4 * lg;
                float4 b4 = *(const float4*)&bi[cb];
                size_t row = row0 + wr * 64 + mi * 16 + ln;
                float v0 = (acc[mi][ni][0] + b4.x) * oscale;
                float v1 = (acc[mi][ni][1] + b4.y) * oscale;
                float v2 = (acc[mi][ni][2] + b4.z) * oscale;
                float v3 = (acc[mi][ni][3] + b4.w) * oscale;
                if (Cf) {
                    float4 o4 = {v0, v1, v2, v3};
                    *(float4*)&Cf[row * DM + cb] = o4;
                } else {
                    bf16x4 pk; pk[0] = (__bf16)v0; pk[1] = (__bf16)v1;
                    pk[2] = (__bf16)v2; pk[3] = (__bf16)v3;
                    *(bf16x4*)&Cb[row * DM + cb] = pk;
                }
            }
    }
}

// Flash cross-attention, bf16, MFMA 16x16x32, m-tile=128, reg-prefetch.
// q is pre-scaled by 1/sqrt(dh)*log2(e); softmax in exp2 domain; defer-max.
// V^T global layout: VcT[b][d=256][m=1024].
__global__ __launch_bounds__(256) void k_attn_mfma(const __bf16* __restrict__ q,
        const __bf16* __restrict__ Kc, const __bf16* __restrict__ VcT,
        const int* __restrict__ starts, __bf16* __restrict__ o) {
    const int b = blockIdx.z, h = blockIdx.y;
    const int r0 = starts[b] + blockIdx.x * 64;
    const int rend = starts[b + 1];
    if (r0 >= rend) return;
    const int nr = min(64, rend - r0);

    __shared__ __bf16 Ks[128][36];   // 18 words/row ≡2 mod 4 -> 1-way frag reads
    __shared__ __bf16 Vt[32][132];   // 66 words/row ≡2 mod 4

    const int t = threadIdx.x;
    const int w = t >> 6, l = t & 63, lg = l >> 4, ln = l & 15;

    const __bf16* Kb = Kc + (size_t)b * MC * DM + h * DH;
    const __bf16* Vb = VcT + ((size_t)b * DM + h * DH) * MC;

    // Q B-fragment (row = ln, k = 4*lg+j | 16+4*lg+j); scale pre-folded
    const int qr = min(r0 + w * 16 + ln, NP - 1);
    const __bf16* qp = q + (size_t)qr * DM + h * DH;
    bf16x4 qlo = *(const bf16x4*)(qp + lg * 4);
    bf16x4 qhi = *(const bf16x4*)(qp + 16 + lg * 4);
    bf16x8 qf = __builtin_shufflevector(qlo, qhi, 0, 1, 2, 3, 4, 5, 6, 7);

    f32x4v Oacc[2] = {{0.f, 0.f, 0.f, 0.f}, {0.f, 0.f, 0.f, 0.f}};
    float mrun = -1e30f, lrun = 0.f;

    const int kr = t >> 2, kc8 = (t & 3) * 8;    // K staging: 64 rows/pass
    const int vr = t >> 4, vc8 = (t & 15) * 8;   // V^T staging: 16 rows/pass

    bf16x8 rk0, rk1, rv0, rv1;
    rk0 = *(const bf16x8*)&Kb[(size_t)kr * DM + kc8];
    rk1 = *(const bf16x8*)&Kb[(size_t)(64 + kr) * DM + kc8];
    rv0 = *(const bf16x8*)&Vb[(size_t)vr * MC + vc8];
    rv1 = *(const bf16x8*)&Vb[(size_t)(16 + vr) * MC + vc8];

    for (int mt = 0; mt < 8; ++mt) {
        __syncthreads();   // prev compute done reading LDS
        *(bf16x8*)&Ks[kr][kc8] = rk0;
        *(bf16x8*)&Ks[64 + kr][kc8] = rk1;
        *(bf16x8*)&Vt[vr][vc8] = rv0;
        *(bf16x8*)&Vt[16 + vr][vc8] = rv1;
        __syncthreads();
        if (mt < 7) {
            const int m0 = (mt + 1) * 128;
            rk0 = *(const bf16x8*)&Kb[(size_t)(m0 + kr) * DM + kc8];
            rk1 = *(const bf16x8*)&Kb[(size_t)(m0 + 64 + kr) * DM + kc8];
            rv0 = *(const bf16x8*)&Vb[(size_t)vr * MC + m0 + vc8];
            rv1 = *(const bf16x8*)&Vb[(size_t)(16 + vr) * MC + m0 + vc8];
        }

        // ---- QK^T (swapped): S[ms][r] = score(q=ln, m = 16ms + 4lg + r) [log2 dom]
        f32x4v S[8];
        __builtin_amdgcn_s_setprio(1);
#pragma unroll
        for (int ms = 0; ms < 8; ++ms) {
            bf16x4 lo = *(const bf16x4*)&Ks[ms * 16 + ln][lg * 4];
            bf16x4 hi = *(const bf16x4*)&Ks[ms * 16 + ln][16 + lg * 4];
            bf16x8 kf = __builtin_shufflevector(lo, hi, 0, 1, 2, 3, 4, 5, 6, 7);
            S[ms] = __builtin_amdgcn_mfma_f32_16x16x32_bf16(
                kf, qf, (f32x4v){0.f, 0.f, 0.f, 0.f}, 0, 0, 0);
        }
        __builtin_amdgcn_s_setprio(0);
        // ---- online softmax (exp2 domain), defer-max
        float tmax = -1e30f;
#pragma unroll
        for (int ms = 0; ms < 8; ++ms)
#pragma unroll
            for (int r = 0; r < 4; ++r) tmax = fmaxf(tmax, S[ms][r]);
        tmax = fmaxf(tmax, __shfl_xor(tmax, 16));
        tmax = fmaxf(tmax, __shfl_xor(tmax, 32));
        if (__any(tmax > mrun + 8.f)) {
            float newm = fmaxf(mrun, tmax);
            float corr = __builtin_amdgcn_exp2f(mrun - newm);
            float c4[4];
#pragma unroll
            for (int r = 0; r < 4; ++r) c4[r] = __shfl(corr, 4 * lg + r);
#pragma unroll
            for (int r = 0; r < 4; ++r) { Oacc[0][r] *= c4[r]; Oacc[1][r] *= c4[r]; }
            lrun *= corr; mrun = newm;
        }
        float psum = 0.f;
#pragma unroll
        for (int ms = 0; ms < 8; ++ms)
#pragma unroll
            for (int r = 0; r < 4; ++r) {
                float e = __builtin_amdgcn_exp2f(S[ms][r] - mrun);
                S[ms][r] = e; psum += e;
            }
        psum += __shfl_xor(psum, 16);
        psum += __shfl_xor(psum, 32);
        lrun += psum;
        // P A-fragments: pa[mh] covers m in [32mh, 32mh+32)
        bf16x8 pa[4];
#pragma unroll
        for (int mh = 0; mh < 4; ++mh)
#pragma unroll
            for (int j = 0; j < 4; ++j) {
                pa[mh][j] = (__bf16)S[2 * mh][j];
                pa[mh][4 + j] = (__bf16)S[2 * mh + 1][j];
            }
        // ---- PV
        __builtin_amdgcn_s_setprio(1);
#pragma unroll
        for (int mh = 0; mh < 4; ++mh)
#pragma unroll
            for (int nt = 0; nt < 2; ++nt) {
                bf16x4 lo = *(const bf16x4*)&Vt[nt * 16 + ln][mh * 32 + lg * 4];
                bf16x4 hi = *(const bf16x4*)&Vt[nt * 16 + ln][mh * 32 + 16 + lg * 4];
                bf16x8 vf = __builtin_shufflevector(lo, hi, 0, 1, 2, 3, 4, 5, 6, 7);
                Oacc[nt] = __builtin_amdgcn_mfma_f32_16x16x32_bf16(pa[mh], vf, Oacc[nt], 0, 0, 0);
            }
        __builtin_amdgcn_s_setprio(0);
    }
    // epilogue
    float inv = 1.0f / lrun;
    float iv[4];
#pragma unroll
    for (int r = 0; r < 4; ++r) iv[r] = __shfl(inv, 4 * lg + r);
#pragma unroll
    for (int r = 0; r < 4; ++r) {
        int rloc = w * 16 + 4 * lg + r;
        if (rloc < nr) {
            size_t base = (size_t)(r0 + rloc) * DM + h * DH + ln;
            o[base] = (__bf16)(Oacc[0][r] * iv[r]);
            o[base + 16] = (__bf16)(Oacc[1][r] * iv[r]);
        }
    }
}

extern "C" void kernel_launch(void* const* d_in, const int* in_sizes, int n_in,
                              void* d_out, int out_size, void* d_ws, size_t ws_size,
                              hipStream_t stream) {
    const float* F  = (const float*)d_in[0];
    const int* bidx = (const int*)d_in[1];
    const float* y  = (const float*)d_in[2];
    const float* Wq = (const float*)d_in[3];
    const float* bq = (const float*)d_in[4];
    const float* Wk = (const float*)d_in[5];
    const float* bk = (const float*)d_in[6];
    const float* Wv = (const float*)d_in[7];
    const float* bv = (const float*)d_in[8];
    const float* Wo = (const float*)d_in[9];
    const float* bo = (const float*)d_in[10];
    const float* lg = (const float*)d_in[11];
    const float* lb = (const float*)d_in[12];
    float* out = (float*)d_out;

    char* ws = (char*)d_ws;
    float* q_in = (float*)ws;                    ws += (size_t)NP * DM * 4;
    float* attn = (float*)ws;                    ws += (size_t)NP * DM * 4;
    __bf16* q_in_b = (__bf16*)ws;                ws += (size_t)NP * DM * 2;
    __bf16* qb     = (__bf16*)ws;                ws += (size_t)NP * DM * 2;
    __bf16* ob     = (__bf16*)ws;                ws += (size_t)NP * DM * 2;
    __bf16* y_b    = (__bf16*)ws;                ws += (size_t)NB * MC * KVD * 2;
    __bf16* Kp     = (__bf16*)ws;                ws += (size_t)NB * MC * DM * 2;
    __bf16* VpT    = (__bf16*)ws;                ws += (size_t)NB * DM * MC * 2;
    __bf16* Wq_b   = (__bf16*)ws;                ws += (size_t)DM * DM * 2;
    __bf16* Wk_b   = (__bf16*)ws;                ws += (size_t)DM * KVD * 2;
    __bf16* Wv_b   = (__bf16*)ws;                ws += (size_t)DM * KVD * 2;
    __bf16* Wo_b   = (__bf16*)ws;                ws += (size_t)DM * DM * 2;
    int* starts    = (int*)ws;

    const float qscale = 0.17677669529663687f * 1.4426950408889634f; // 1/sqrt(32)*log2(e)

    k_starts<<<1, 64, 0, stream>>>(bidx, starts);
    k_conv<<<2432, 256, 0, stream>>>(y, Wq, Wk, Wv, Wo, y_b, Wq_b, Wk_b, Wv_b, Wo_b);
    k_ln4<<<NP / 4, 256, 0, stream>>>(F, nullptr, lg, lb, q_in, q_in_b);
    // Q projection (bf16 out, scaled)
    k_gemm<<<dim3(4, NP / 128), 256, 0, stream>>>(q_in_b, Wq_b, bq, nullptr, nullptr,
                                                  nullptr, qb, nullptr, DM, qscale);
    // K (row-major) + V (transposed) fused
    k_gemm<<<dim3(8, (NB * MC) / 128), 256, 0, stream>>>(y_b, Wk_b, bk, Wv_b, bv,
                                                  nullptr, Kp, VpT, KVD, 1.0f);
    k_attn_mfma<<<dim3(NP / 64, NH, NB), 256, 0, stream>>>(qb, Kp, VpT, starts, ob);
    // Wo projection (fp32 out)
    k_gemm<<<dim3(4, NP / 128), 256, 0, stream>>>(ob, Wo_b, bo, nullptr, nullptr,
                                                  attn, nullptr, nullptr, DM, 1.0f);
    k_ln4<<<NP / 4, 256, 0, stream>>>(q_in, attn, lg, lb, out, nullptr);
}